// Round 14
// baseline (60.320 us; speedup 1.0000x reference)
//
#include <hip/hip_runtime.h>
#include <hip/hip_bf16.h>
#include <stdint.h>

#define G1CAST(p) ((const __attribute__((address_space(1))) void*)(p))
#define L3CAST(p) ((__attribute__((address_space(3))) void*)(p))

typedef short bf16x8 __attribute__((ext_vector_type(8)));
typedef float f32x16 __attribute__((ext_vector_type(16)));

static __device__ __forceinline__ short f2bf(float f) {
    __hip_bfloat16 b = __float2bfloat16(f);
    return __builtin_bit_cast(short, b);
}

// ---------------------------------------------------------------------------
// Kernel 1: weights -> bf16, step-block layout.
// Wstep[(nblk*8+jt)*64+s] is a contiguous 6144B block:
//   [wn 0..1][g 0..2][lane 0..63][16B]   (= (wn*3+g)*1024 + lane*16)
// Fragment semantics (mfma_f32_32x32x16_bf16 B operand):
//   j  = jt*64 + wn*32 + (lane&31),  kk = s*16 + (lane>>5)*8 + t, t=0..7
//   kk<512 -> W_ih[nblk][g*512+j][kk], else W_hh[nblk][g*512+j][kk-512]
// Writer XCD (b%8) == consumer XCD (nblk).
// ---------------------------------------------------------------------------
__global__ __launch_bounds__(256) void wconv_kernel(const float* __restrict__ Wih,
                                                    const float* __restrict__ Whh,
                                                    short* __restrict__ Wstep) {
    const int b = blockIdx.x;                         // 6144
    const int vb = (b & 7) * 768 + (b >> 3);          // XCD-aligned permute
    const int gid = vb * 256 + threadIdx.x;
    const int lane = gid & 63;
    int t1 = gid >> 6;
    const int g = t1 % 3;  t1 /= 3;
    const int wn = t1 & 1; t1 >>= 1;
    const int s = t1 & 63; t1 >>= 6;
    const int jt = t1 & 7;
    const int nblk = t1 >> 3;
    const int j = jt * 64 + wn * 32 + (lane & 31);
    const int kk = s * 16 + (lane >> 5) * 8;
    const float* src = (kk < 512)
        ? Wih + ((int64_t)nblk * 786432 + (int64_t)(g * 512 + j) * 512 + kk)
        : Whh + ((int64_t)nblk * 786432 + (int64_t)(g * 512 + j) * 512 + (kk - 512));
    const float4 a = ((const float4*)src)[0];
    const float4 bq = ((const float4*)src)[1];
    bf16x8 o;
    o[0] = f2bf(a.x); o[1] = f2bf(a.y); o[2] = f2bf(a.z); o[3] = f2bf(a.w);
    o[4] = f2bf(bq.x); o[5] = f2bf(bq.y); o[6] = f2bf(bq.z); o[7] = f2bf(bq.w);
    *(bf16x8*)(Wstep + (size_t)gid * 8) = o;
}

// ---------------------------------------------------------------------------
// Kernel 1b: x,h -> bf16 A-image in MFMA fragment order (R11-proven).
// Afrag[rb 0..31][nblk 0..7][s 0..63][lane 0..63][8 bf16]:
//   row = rb*32 + (lane&31),  kk = s*16 + (lane>>5)*8  (kk<512 = x, else h)
// ---------------------------------------------------------------------------
__global__ __launch_bounds__(256) void aconv_kernel(const float* __restrict__ x,
                                                    const float* __restrict__ h,
                                                    short* __restrict__ Afrag) {
    const int b = blockIdx.x;                 // 4096
    const int n = b & 7;                      // == consumer XCD
    const int inner = b >> 3;                 // 0..511
    const int rb = inner >> 4;                // 0..31
    const int u = inner & 15;                 // 0..15
    const int tid = threadIdx.x;
    const int lane = tid & 63;
    const int s = u * 4 + (tid >> 6);         // 0..63
    const int row = rb * 32 + (lane & 31);
    const int kk = s * 16 + (lane >> 5) * 8;  // 0..1023
    const float* src = (kk < 512)
        ? x + ((size_t)row * 4096 + n * 512 + kk)
        : h + ((size_t)row * 4096 + n * 512 + (kk - 512));
    const float4 a = ((const float4*)src)[0];
    const float4 bq = ((const float4*)src)[1];
    bf16x8 o;
    o[0] = f2bf(a.x); o[1] = f2bf(a.y); o[2] = f2bf(a.z); o[3] = f2bf(a.w);
    o[4] = f2bf(bq.x); o[5] = f2bf(bq.y); o[6] = f2bf(bq.z); o[7] = f2bf(bq.w);
    const size_t dst = ((((size_t)(rb * 8 + n) * 64 + s) * 64) + lane) * 8;
    *(bf16x8*)(Afrag + dst) = o;
}

// ---------------------------------------------------------------------------
// Kernel 2: fused block-diagonal GRU.
// BM=128 x BN=64(x3 gates), 256 thr = 4 waves (2wm x 2wn), wave tile 64x32
// (m_rep=2), acc = 8 x f32x16 = 128 regs. Grid 512 = 2 blocks/CU.
// B: shared LDS ring-6, slot 8192B (6144 real + 2048 pad), staged by a
// UNIFORM 2 x 16B global_load_lds per wave per step (wave 3 stages pad with
// duplicated valid bytes). Raw s_barrier + counted vmcnt(12), sched_barrier
// pinned. A: private register prefetch depth-3 (4 named sets).
// ---------------------------------------------------------------------------
__global__ __launch_bounds__(256, 2) void gru_kernel(
    const float* __restrict__ hst,
    const short* __restrict__ Wstep, const short* __restrict__ Afrag,
    const float* __restrict__ b_ih, const float* __restrict__ b_hh,
    float* __restrict__ out)
{
    __shared__ char ldsB[6][8192];            // 48 KB ring

    const int tid = threadIdx.x;
    const int nblk = blockIdx.x & 7;          // XCD-local weight slice
    const int rr_ = blockIdx.x >> 3;          // 0..63
    const int bt = rr_ >> 3;                  // 0..7 batch tile (slow)
    const int jt = rr_ & 7;                   // j tile (fast -> A L2 reuse)
    const int brow0 = bt * 128;

    const int lane = tid & 63;
    const int wave = tid >> 6;                // 0..3
    const int wm = wave >> 1;                 // 0..1 (64-row slice)
    const int wn = wave & 1;                  // 0..1 (32-col slice)
    const int l31 = lane & 31;
    const int k8 = lane >> 5;

    // A fragment streams (private, register-prefetched)
    const int rb0 = (brow0 + wm * 64) >> 5;
    const char* ab0 = (const char*)Afrag + ((size_t)(rb0 * 8 + nblk) << 16) + (size_t)lane * 16;
    const char* ab1 = ab0 + (8 << 16);        // rb0 + 1

    // B staging: wave w stages dest [w*2048, w*2048+2048) of the 8192B slot,
    // as 2 x 16B per lane. Pad region (>=6144) re-reads valid bytes.
    const int d0 = wave * 2048;
    const int ssrc0 = (d0 >= 6144) ? d0 - 6144 : d0;
    const int ssrc1 = (d0 + 1024 >= 6144) ? d0 + 1024 - 6144 : d0 + 1024;
    const char* wstep0 = (const char*)Wstep + (size_t)((nblk * 8 + jt) * 64) * 6144
                       + (size_t)lane * 16;
    // B read offset within a slot (real region only)
    const int boff = (wn * 3) * 1024 + lane * 16;

    f32x16 acc_r[2] = {};
    f32x16 acc_z[2] = {};
    f32x16 acc_nx[2] = {};
    f32x16 acc_nh[2] = {};

    bf16x8 a0P, a1P, a0Q, a1Q, a0R, a1R, a0S, a1S;

#define LDA(T, s_v)                                                        \
    {                                                                      \
        const int sc = (s_v) > 63 ? 63 : (s_v);                            \
        a0##T = *(const bf16x8*)(ab0 + (size_t)sc * 1024);                 \
        a1##T = *(const bf16x8*)(ab1 + (size_t)sc * 1024);                 \
    }

    auto stageB = [&](int s, int slot) {
        const int sc = s > 63 ? 63 : s;
        const char* src = wstep0 + (size_t)sc * 6144;
        char* dst = (char*)&ldsB[slot][0] + d0;
        __builtin_amdgcn_global_load_lds(G1CAST(src + ssrc0), L3CAST(dst), 16, 0, 0);
        __builtin_amdgcn_global_load_lds(G1CAST(src + ssrc1), L3CAST(dst + 1024), 16, 0, 0);
    };

#define ITER(C, L, accN)                                                            \
    {                                                                               \
        __builtin_amdgcn_s_barrier();                                               \
        __builtin_amdgcn_sched_barrier(0);                                          \
        stageB(s_ + 5, wslot);                                                      \
        LDA(L, s_ + 3)                                                              \
        __builtin_amdgcn_sched_barrier(0);                                          \
        asm volatile("s_waitcnt vmcnt(12)" ::: "memory");                           \
        __builtin_amdgcn_sched_barrier(0);                                          \
        const char* bp = &ldsB[rslot][boff];                                        \
        bf16x8 b0 = *(const bf16x8*)(bp);                                           \
        bf16x8 b1 = *(const bf16x8*)(bp + 1024);                                    \
        bf16x8 b2 = *(const bf16x8*)(bp + 2048);                                    \
        __builtin_amdgcn_s_setprio(1);                                              \
        acc_r[0] = __builtin_amdgcn_mfma_f32_32x32x16_bf16(a0##C, b0, acc_r[0], 0, 0, 0); \
        acc_r[1] = __builtin_amdgcn_mfma_f32_32x32x16_bf16(a1##C, b0, acc_r[1], 0, 0, 0); \
        acc_z[0] = __builtin_amdgcn_mfma_f32_32x32x16_bf16(a0##C, b1, acc_z[0], 0, 0, 0); \
        acc_z[1] = __builtin_amdgcn_mfma_f32_32x32x16_bf16(a1##C, b1, acc_z[1], 0, 0, 0); \
        accN[0]  = __builtin_amdgcn_mfma_f32_32x32x16_bf16(a0##C, b2, accN[0], 0, 0, 0);  \
        accN[1]  = __builtin_amdgcn_mfma_f32_32x32x16_bf16(a1##C, b2, accN[1], 0, 0, 0);  \
        __builtin_amdgcn_s_setprio(0);                                              \
        rslot = (rslot == 5) ? 0 : rslot + 1;                                       \
        wslot = (wslot == 5) ? 0 : wslot + 1;                                       \
        s_ += 1;                                                                    \
    }

    // prologue: B(0..4) into slots 0..4, A(0..2) into P,Q,R
    stageB(0, 0); stageB(1, 1); stageB(2, 2); stageB(3, 3); stageB(4, 4);
    LDA(P, 0) LDA(Q, 1) LDA(R, 2)
    __builtin_amdgcn_sched_barrier(0);
    asm volatile("s_waitcnt vmcnt(12)" ::: "memory");   // B(0),B(1) landed
    __builtin_amdgcn_sched_barrier(0);

    int s_ = 0;
    int rslot = 0;                            // s % 6
    int wslot = 5;                            // (s+5) % 6

    #pragma unroll 1
    for (int g4 = 0; g4 < 8; ++g4) {          // steps 0..31 -> acc_nx
        ITER(P, S, acc_nx)
        ITER(Q, P, acc_nx)
        ITER(R, Q, acc_nx)
        ITER(S, R, acc_nx)
    }
    #pragma unroll 1
    for (int g4 = 0; g4 < 8; ++g4) {          // steps 32..63 -> acc_nh
        ITER(P, S, acc_nh)
        ITER(Q, P, acc_nh)
        ITER(R, Q, acc_nh)
        ITER(S, R, acc_nh)
    }
#undef ITER
#undef LDA

    // ---- epilogue: gates + output (wave owns 64x32 tile) ----
    const int jb = jt * 64 + wn * 32 + l31;   // [0,512)
    const int bb = nblk * 1536 + jb;
    const float br = b_ih[bb] + b_hh[bb];
    const float bz = b_ih[bb + 512] + b_hh[bb + 512];
    const float bnx = b_ih[bb + 1024];
    const float bnh = b_hh[bb + 1024];
    const int gcol = nblk * 512 + jb;
    #pragma unroll
    for (int m = 0; m < 2; ++m) {
        #pragma unroll
        for (int rr = 0; rr < 16; ++rr) {
            const int rowl = (rr & 3) + 8 * (rr >> 2) + 4 * k8;
            const int row = brow0 + wm * 64 + m * 32 + rowl;
            const size_t idx = (size_t)row * 4096 + gcol;
            const float sr = acc_r[m][rr] + br;
            const float sz = acc_z[m][rr] + bz;
            const float rg = 1.f / (1.f + __expf(-sr));
            const float zg = 1.f / (1.f + __expf(-sz));
            const float tin = (acc_nx[m][rr] + bnx) + rg * (acc_nh[m][rr] + bnh);
            const float e2 = __expf(-2.f * tin);
            const float ng = 2.f / (1.f + e2) - 1.f;
            const float hv = hst[idx];
            out[idx] = ng + zg * (hv - ng);
        }
    }
}

extern "C" void kernel_launch(void* const* d_in, const int* in_sizes, int n_in,
                              void* d_out, int out_size, void* d_ws, size_t ws_size,
                              hipStream_t stream) {
    (void)in_sizes; (void)n_in; (void)out_size; (void)ws_size;
    const float* x    = (const float*)d_in[0];
    const float* h    = (const float*)d_in[1];
    const float* W_ih = (const float*)d_in[2];
    const float* W_hh = (const float*)d_in[3];
    const float* b_ih = (const float*)d_in[4];
    const float* b_hh = (const float*)d_in[5];
    short* Wstep = (short*)d_ws;                              // 24 MB
    short* Afrag = (short*)d_ws + (size_t)12 * 1024 * 1024;   // 16 MB

    wconv_kernel<<<6144, 256, 0, stream>>>(W_ih, W_hh, Wstep);
    aconv_kernel<<<4096, 256, 0, stream>>>(x, h, Afrag);
    gru_kernel<<<512, 256, 0, stream>>>(h, Wstep, Afrag, b_ih, b_hh, (float*)d_out);
}